// Round 3
// baseline (11000.079 us; speedup 1.0000x reference)
//
#include <hip/hip_runtime.h>
#include <cmath>

#define HID 512
#define NEXP 128
#define BB 4
#define SS 2048
#define NROW (BB*SS)      // 8192
#define FAST_ITERS 96
#define FAIL_STICKY 12

typedef unsigned long long u64;
typedef unsigned int u32;

__device__ __forceinline__ float gelu_f(float x){
  return 0.5f*x*(1.0f + erff(x*0.70710678118654752440f));
}

__device__ __forceinline__ u64 aload64(const u64* p){
  return __hip_atomic_load(p, __ATOMIC_RELAXED, __HIP_MEMORY_SCOPE_AGENT);
}
__device__ __forceinline__ void astore64(u64* p, u64 v){
  __hip_atomic_store(p, v, __ATOMIC_RELAXED, __HIP_MEMORY_SCOPE_AGENT);
}
// plain store: write-through L1 -> local XCD L2 (fast same-XCD visibility)
__device__ __forceinline__ void fstore64(u64* p, u64 v){
  asm volatile("global_store_dwordx2 %0, %1, off" :: "v"(p), "v"(v) : "memory");
}
__device__ __forceinline__ u64 packtag(float f, u32 tag){
  return ((u64)__float_as_uint(f) << 32) | (u64)tag;
}

// poll 2 words: fast path = sc0 loads (local-XCD L2); fallback = agent mirror
__device__ __forceinline__ void poll2x(const u64* fb, const u64* mb, u32 tag,
                                       float* stg, int tid,
                                       int& fails, bool& use_agent){
  u64 v0 = 0, v1 = 0;
  bool ok0 = false, ok1 = false;
  if (!use_agent){
    const u64* p0 = fb + tid;
    const u64* p1 = fb + tid + 256;
    for (int it = 0; it < FAST_ITERS; ++it){
      u64 a, b;
      asm volatile("global_load_dwordx2 %0, %2, off sc0\n\t"
                   "global_load_dwordx2 %1, %3, off sc0\n\t"
                   "s_waitcnt vmcnt(0)"
                   : "=&v"(a), "=&v"(b) : "v"(p0), "v"(p1) : "memory");
      if (!ok0 && (u32)a == tag){ ok0 = true; v0 = a; }
      if (!ok1 && (u32)b == tag){ ok1 = true; v1 = b; }
      if (ok0 && ok1) break;
    }
    if (!(ok0 && ok1)){
      if (++fails >= FAIL_STICKY) use_agent = true;
    }
  }
  if (!ok0){ const u64* q = mb + tid;       u64 a; do { a = aload64(q); } while ((u32)a != tag); v0 = a; }
  if (!ok1){ const u64* q = mb + tid + 256; u64 a; do { a = aload64(q); } while ((u32)a != tag); v1 = a; }
  stg[tid]       = __uint_as_float((u32)(v0 >> 32));
  stg[tid + 256] = __uint_as_float((u32)(v1 >> 32));
}

// ---------------- biwc = b_iw + input_b --------------------------------------
__global__ __launch_bounds__(256) void biwc_k(const float* __restrict__ b_iw,
                                              const float* __restrict__ input_b,
                                              float* __restrict__ biwc)
{
  int i = blockIdx.x*256 + threadIdx.x;
  if (i < HID) biwc[i] = b_iw[i] + input_b[i];
}

// ---------------- generic fp32 GEMM: C = A(MxK) @ W(KxN) + bias (opt gelu) --
template<bool GELU>
__global__ __launch_bounds__(256) void gemm_k(
    const float* __restrict__ A, const float* __restrict__ W,
    const float* __restrict__ bias, float* __restrict__ C,
    int M, int N, int K)
{
  __shared__ float As[16][68];
  __shared__ float Ws[16][68];
  const int tid = threadIdx.x;
  const int mb = blockIdx.y*64, nb = blockIdx.x*64;
  const int tx = tid & 15, ty = tid >> 4;
  const int am = tid >> 2, ak = (tid & 3)*4;
  const int wk = tid >> 4, wn = (tid & 15)*4;
  float acc[4][4] = {};
  const float* Aptr = A + (size_t)(mb+am)*K + ak;
  for (int kt = 0; kt < K; kt += 16){
    float4 av = *(const float4*)(Aptr + kt);
    float4 wv = *(const float4*)(W + (size_t)(kt+wk)*N + nb + wn);
    As[ak  ][am] = av.x; As[ak+1][am] = av.y; As[ak+2][am] = av.z; As[ak+3][am] = av.w;
    *(float4*)&Ws[wk][wn] = wv;
    __syncthreads();
#pragma unroll
    for (int kk = 0; kk < 16; kk++){
      float4 a4 = *(const float4*)&As[kk][ty*4];
      float4 w4 = *(const float4*)&Ws[kk][tx*4];
      float ar[4] = {a4.x, a4.y, a4.z, a4.w};
      float wr[4] = {w4.x, w4.y, w4.z, w4.w};
#pragma unroll
      for (int i = 0; i < 4; i++)
#pragma unroll
        for (int j = 0; j < 4; j++)
          acc[i][j] = fmaf(ar[i], wr[j], acc[i][j]);
    }
    __syncthreads();
  }
#pragma unroll
  for (int i = 0; i < 4; i++){
    int row = mb + ty*4 + i;
    float o[4];
#pragma unroll
    for (int j = 0; j < 4; j++){
      float v = acc[i][j] + bias[nb + tx*4 + j];
      o[j] = GELU ? gelu_f(v) : v;
    }
    float4 o4 = {o[0], o[1], o[2], o[3]};
    *(float4*)(C + (size_t)row*N + nb + tx*4) = o4;
  }
}

// ---------------- sequential h-recurrence (XCD-local fast exchange) ----------
__global__ __launch_bounds__(256, 1) void scan_k(
    const float* __restrict__ w_ff1, const float* __restrict__ w_rw,
    const float* __restrict__ w_ff2,
    const float* __restrict__ w_ta, const float* __restrict__ w_tb,
    const float* __restrict__ bff2, const float* __restrict__ b_ta,
    const float* __restrict__ b_tb, const float* __restrict__ rb,
    const float* __restrict__ PRE, const float* __restrict__ INPC,
    float* __restrict__ Hout,
    u64* __restrict__ exh, u64* __restrict__ exf1, u64* __restrict__ exf2,
    u64* __restrict__ fexh, u64* __restrict__ fexf1, u64* __restrict__ fexf2)
{
  __shared__ float Wa2[512*32];   // 64 KB
  __shared__ float Wb2[512*16];   // 32 KB
  __shared__ float Wc2[512*16];   // 32 KB
  __shared__ float stg[512];
  __shared__ float red[128];
  __shared__ float rec_loc[16];

  const int tid = threadIdx.x;
  const int b = blockIdx.x & 7;          // chain = XCD (bid%8 round-robin)
  if (b >= BB) return;
  const int sub = blockIdx.x >> 3;       // 0..31 within chain
  const int col0 = sub*16;
  u64* exh_b   = exh   + b*512;
  u64* exf1_b  = exf1  + b*512;
  u64* exf2_b  = exf2  + b*512;
  u64* fexh_b  = fexh  + b*512;
  u64* fexf1_b = fexf1 + b*512;
  u64* fexf2_b = fexf2 + b*512;

  // publish initial h (tag 0) through local L2 (mirror already zeroed = tag0)
  if (tid < 16) fstore64(&fexh_b[col0 + tid], packtag(0.f, 0u));

  // ---- preload weight slices into LDS (paired-k) ----
  for (int idx = tid; idx < 512*32; idx += 256){
    int k = idx >> 5, c = idx & 31;
    float v = (c < 16) ? w_ff1[(size_t)(512+k)*HID + col0 + c]
                       : w_rw[(size_t)k*HID + col0 + (c-16)];
    Wa2[((k>>1)<<6) + (c<<1) + (k&1)] = v;
  }
  for (int idx = tid; idx < 512*16; idx += 256){
    int k = idx >> 4, c = idx & 15;
    Wb2[((k>>1)<<5) + (c<<1) + (k&1)] = w_ff2[(size_t)k*HID + col0 + c];
    Wc2[((k>>1)<<5) + (c<<1) + (k&1)] = w_ta[(size_t)k*HID + col0 + c]
                                      + w_tb[(size_t)k*HID + col0 + c];
  }
  float b3v = 0.f, bff2v = 0.f, rbv = 0.f, h_reg = 0.f;
  if (tid < 16){ b3v = b_ta[col0+tid] + b_tb[col0+tid]; bff2v = bff2[col0+tid]; }
  if (tid >= 16 && tid < 32) rbv = rb[col0 + tid - 16];
  __syncthreads();

  const int cA = tid & 31, pA = tid >> 5;   // stage A: 32 outs x 8 k-parts
  const int cB = tid & 15, pB = tid >> 4;   // stage B/C: 16 outs x 16 k-parts
  int fails = 0; bool use_agent = false;

  for (int t = 0; t < SS; t++){
    float pre_v = 0.f, ic_v = 0.f;
    if (tid < 16){
      pre_v = PRE [((size_t)b*SS + t)*HID + col0 + tid];
      ic_v  = INPC[((size_t)b*SS + t)*HID + col0 + tid];
    }
    // ---- gather h (tag t) ----
    poll2x(fexh_b, exh_b, (u32)t, stg, tid, fails, use_agent);
    __syncthreads();
    // ---- stage A: [ff1_h | rec] = h @ Wa ----
    {
      const float2* wp = (const float2*)(Wa2) + (pA<<5) + cA;
      const float2* hp = (const float2*)(stg) + pA;
      float a0=0.f, a1=0.f, a2=0.f, a3=0.f;
#pragma unroll
      for (int j = 0; j < 32; j += 2){
        float2 w0 = wp[(j+0)*256], h0 = hp[(j+0)*8];
        float2 w1 = wp[(j+1)*256], h1 = hp[(j+1)*8];
        a0 = fmaf(w0.x, h0.x, a0); a1 = fmaf(w0.y, h0.y, a1);
        a2 = fmaf(w1.x, h1.x, a2); a3 = fmaf(w1.y, h1.y, a3);
      }
      float acc = (a0+a1)+(a2+a3);
      acc += __shfl_xor(acc, 32);
      if ((tid & 32) == 0) red[(tid>>6)*32 + cA] = acc;
    }
    __syncthreads();
    if (tid < 32){
      float s = red[tid] + red[32+tid] + red[64+tid] + red[96+tid];
      if (tid < 16){
        float v = gelu_f(pre_v + s);
        u64 pk = packtag(v, (u32)(t+1));
        fstore64(&fexf1_b[col0 + tid], pk);
        astore64(&exf1_b[col0 + tid], pk);
      } else {
        rec_loc[tid-16] = gelu_f(s + rbv);
      }
    }
    // ---- gather ff1 (tag t+1) ----
    poll2x(fexf1_b, exf1_b, (u32)(t+1), stg, tid, fails, use_agent);
    __syncthreads();
    // ---- stage B: ff2 = gelu(ff1 @ Wb + b) ----
    {
      const float2* wp = (const float2*)(Wb2) + (pB<<4) + cB;
      const float2* hp = (const float2*)(stg) + pB;
      float a0=0.f, a1=0.f, a2=0.f, a3=0.f;
#pragma unroll
      for (int j = 0; j < 16; j += 2){
        float2 w0 = wp[(j+0)*256], h0 = hp[(j+0)*16];
        float2 w1 = wp[(j+1)*256], h1 = hp[(j+1)*16];
        a0 = fmaf(w0.x, h0.x, a0); a1 = fmaf(w0.y, h0.y, a1);
        a2 = fmaf(w1.x, h1.x, a2); a3 = fmaf(w1.y, h1.y, a3);
      }
      float acc = (a0+a1)+(a2+a3);
      acc += __shfl_xor(acc, 16);
      acc += __shfl_xor(acc, 32);
      if ((tid & 48) == 0) red[(tid>>6)*16 + cB] = acc;
    }
    __syncthreads();
    if (tid < 16){
      float s = red[tid] + red[16+tid] + red[32+tid] + red[48+tid];
      float v = gelu_f(s + bff2v);
      u64 pk = packtag(v, (u32)(t+1));
      fstore64(&fexf2_b[col0 + tid], pk);
      astore64(&exf2_b[col0 + tid], pk);
    }
    // ---- gather ff2 (tag t+1) ----
    poll2x(fexf2_b, exf2_b, (u32)(t+1), stg, tid, fails, use_agent);
    __syncthreads();
    // ---- stage C: t_interp + new_h ----
    {
      const float2* wp = (const float2*)(Wc2) + (pB<<4) + cB;
      const float2* hp = (const float2*)(stg) + pB;
      float a0=0.f, a1=0.f, a2=0.f, a3=0.f;
#pragma unroll
      for (int j = 0; j < 16; j += 2){
        float2 w0 = wp[(j+0)*256], h0 = hp[(j+0)*16];
        float2 w1 = wp[(j+1)*256], h1 = hp[(j+1)*16];
        a0 = fmaf(w0.x, h0.x, a0); a1 = fmaf(w0.y, h0.y, a1);
        a2 = fmaf(w1.x, h1.x, a2); a3 = fmaf(w1.y, h1.y, a3);
      }
      float acc = (a0+a1)+(a2+a3);
      acc += __shfl_xor(acc, 16);
      acc += __shfl_xor(acc, 32);
      if ((tid & 48) == 0) red[(tid>>6)*16 + cB] = acc;
    }
    __syncthreads();
    if (tid < 16){
      float s = red[tid] + red[16+tid] + red[32+tid] + red[48+tid];
      float ti = 1.0f / (1.0f + expf(-(s + b3v)));
      float nh = h_reg*(1.0f - ti) + ti*(ic_v + rec_loc[tid]);
      h_reg = nh;
      u64 pk = packtag(nh, (u32)(t+1));
      fstore64(&fexh_b[col0 + tid], pk);
      astore64(&exh_b[col0 + tid], pk);
      Hout[((size_t)b*SS + t)*HID + col0 + tid] = nh;
    }
  }

  // ---- poison sweep: kill stale fast-buffer tags for the next call ----
  __syncthreads();
  for (int i = tid; i < 512; i += 256){
    fstore64(&fexh_b[i],  0xFFFFFFFFull);
    fstore64(&fexf1_b[i], 0xFFFFFFFFull);
    fstore64(&fexf2_b[i], 0xFFFFFFFFull);
  }
}

// ---------------- softmax over 128 experts ----------------------------------
__global__ __launch_bounds__(256) void softmax_k(const float* __restrict__ LOGITS,
                                                 float* __restrict__ SM)
{
  int wv = threadIdx.x >> 6, lane = threadIdx.x & 63;
  int row = blockIdx.x*4 + wv;
  const float* xp = LOGITS + (size_t)row*NEXP;
  float x0 = xp[lane], x1 = xp[lane+64];
  float m = fmaxf(x0, x1);
#pragma unroll
  for (int d = 1; d < 64; d <<= 1) m = fmaxf(m, __shfl_xor(m, d));
  float e0 = expf(x0 - m), e1 = expf(x1 - m);
  float s = e0 + e1;
#pragma unroll
  for (int d = 1; d < 64; d <<= 1) s += __shfl_xor(s, d);
  float inv = 1.0f / s;
  float* op = SM + (size_t)row*NEXP;
  op[lane] = e0*inv; op[lane+64] = e1*inv;
}

// ---------------- smoothing (20-term window == exact recurrence) + top2 -----
__global__ __launch_bounds__(256) void smooth_topk_k(const float* __restrict__ SM,
                                                     float* __restrict__ out)
{
  int wv = threadIdx.x >> 6, lane = threadIdx.x & 63;
  int row = blockIdx.x*4 + wv;
  int b = row >> 11, t = row & 2047;
  const float* base = SM + (size_t)row*NEXP;
  float a0 = 0.f, a1 = 0.f;
  float coef = 0.9f;
  int nt = t < 20 ? t : 20;
  for (int j = 0; j < nt; j++){
    const float* pj = base - j*NEXP;
    a0 += coef * pj[lane];
    a1 += coef * pj[lane+64];
    coef *= 0.1f;
  }
  if (t < 20){
    const float* s0 = SM + (size_t)b*SS*NEXP;
    float c0 = coef * (1.0f/0.9f);    // 0.1^t
    a0 += c0 * s0[lane];
    a1 += c0 * s0[lane+64];
  }
  float v0, v1; int i0, i1;
  if (a0 >= a1){ v0=a0; i0=lane;    v1=a1; i1=lane+64; }
  else         { v0=a1; i0=lane+64; v1=a0; i1=lane;    }
#pragma unroll
  for (int d = 1; d < 64; d <<= 1){
    float ov0 = __shfl_xor(v0, d), ov1 = __shfl_xor(v1, d);
    int   oi0 = __shfl_xor(i0, d), oi1 = __shfl_xor(i1, d);
    bool firstMine = (v0 > ov0) || (v0 == ov0 && i0 < oi0);
    float nv0, nv1; int ni0, ni1;
    if (firstMine){
      nv0 = v0; ni0 = i0;
      bool s = (v1 > ov0) || (v1 == ov0 && i1 < oi0);
      nv1 = s ? v1 : ov0; ni1 = s ? i1 : oi0;
    } else {
      nv0 = ov0; ni0 = oi0;
      bool s = (ov1 > v0) || (ov1 == v0 && oi1 < i0);
      nv1 = s ? ov1 : v0; ni1 = s ? oi1 : i0;
    }
    v0 = nv0; v1 = nv1; i0 = ni0; i1 = ni1;
  }
  if (lane == 0){
    float ssum = v0 + v1;
    size_t o = (size_t)row*2;
    out[o]     = (float)i0;
    out[o+1]   = (float)i1;
    out[16384 + o]   = v0 / ssum;
    out[16384 + o+1] = v1 / ssum;
  }
}

// ---------------- host launch ------------------------------------------------
extern "C" void kernel_launch(void* const* d_in, const int* in_sizes, int n_in,
                              void* d_out, int out_size, void* d_ws, size_t ws_size,
                              hipStream_t stream)
{
  (void)in_sizes; (void)n_in; (void)out_size;
  const float* x       = (const float*)d_in[0];
  const float* w_in    = (const float*)d_in[1];
  const float* b_in    = (const float*)d_in[2];
  const float* w_ff1   = (const float*)d_in[3];
  const float* b_ff1   = (const float*)d_in[4];
  const float* w_ff2   = (const float*)d_in[5];
  const float* b_ff2   = (const float*)d_in[6];
  const float* w_ta    = (const float*)d_in[7];
  const float* b_ta    = (const float*)d_in[8];
  const float* w_tb    = (const float*)d_in[9];
  const float* b_tb    = (const float*)d_in[10];
  const float* w_iw    = (const float*)d_in[11];
  const float* b_iw    = (const float*)d_in[12];
  const float* input_b = (const float*)d_in[13];
  const float* w_rw    = (const float*)d_in[14];
  const float* r_b     = (const float*)d_in[15];
  const float* w_g1    = (const float*)d_in[16];
  const float* b_g1    = (const float*)d_in[17];
  const float* w_g2    = (const float*)d_in[18];
  const float* b_g2    = (const float*)d_in[19];

  float* ws    = (float*)d_ws;
  float* XT    = ws + 0;               // 8192*512
  float* PRE   = ws + 4194304;         // 8192*512
  float* INPC  = ws + 8388608;         // 8192*512
  float* Hbuf  = ws + 12582912;        // 8192*512
  float* G1    = ws + 0;               // reuse XT+PRE after scan (8192*1024)
  float* LOGB  = ws + 8388608;         // reuse INPC (8192*128)
  float* SM    = ws + 9437184;         // 8192*128
  float* biwc  = ws + 16777216;        // 512
  u64*   exh   = (u64*)(ws + 16777728);// mirrors: 4*512 u64 each
  u64*   exf1  = (u64*)(ws + 16781824);
  u64*   exf2  = (u64*)(ws + 16785920);
  u64*   fexh  = (u64*)(ws + 16790016);// fast: 4*512 u64 each
  u64*   fexf1 = (u64*)(ws + 16794112);
  u64*   fexf2 = (u64*)(ws + 16798208);
  if (ws_size < (size_t)16802304 * sizeof(float)) return;

  // reset mirror tags only (fast buffers are self-poisoning)
  hipMemsetAsync(ws + 16777728, 0, 3 * 2048 * sizeof(u64), stream);

  biwc_k<<<2, 256, 0, stream>>>(b_iw, input_b, biwc);
  gemm_k<false><<<dim3(8, 128), 256, 0, stream>>>(x, w_in, b_in, XT, NROW, 512, 4096);
  gemm_k<false><<<dim3(8, 128), 256, 0, stream>>>(XT, w_ff1, b_ff1, PRE, NROW, 512, 512);
  gemm_k<true ><<<dim3(8, 128), 256, 0, stream>>>(XT, w_iw, biwc, INPC, NROW, 512, 512);
  scan_k<<<256, 256, 0, stream>>>(w_ff1, w_rw, w_ff2, w_ta, w_tb,
                                  b_ff2, b_ta, b_tb, r_b,
                                  PRE, INPC, Hbuf, exh, exf1, exf2,
                                  fexh, fexf1, fexf2);
  gemm_k<true ><<<dim3(16, 128), 256, 0, stream>>>(Hbuf, w_g1, b_g1, G1, NROW, 1024, 512);
  gemm_k<false><<<dim3(2, 128), 256, 0, stream>>>(G1, w_g2, b_g2, LOGB, NROW, 128, 1024);
  softmax_k<<<2048, 256, 0, stream>>>(LOGB, SM);
  smooth_topk_k<<<2048, 256, 0, stream>>>(SM, (float*)d_out);
}